// Round 3
// baseline (1535.234 us; speedup 1.0000x reference)
//
#include <hip/hip_runtime.h>

#define H 2048
#define E 16
#define F 1408
#define FS 4096
#define T 2048
#define TOPK 4
#define CAP 2048
#define NPADROWS (T * TOPK + E * 128)  // 10240 padded expert slots
#define NMB (NPADROWS / 128)           // 80 expert m-blocks max
#define NS ((FS / 128) * (T / 128))    // 512 shared s1 blocks
#define GS1 (NS + (F / 128) * NMB)     // 512 + 880 = 1392
#define GS2 ((H / 128) * (T / 128) + (H / 128) * NMB)  // 256 + 1280 = 1536

// prep grid pieces
#define TPE ((H / 64) * (F / 64))      // 704 tiles per expert tensor
#define NT_E (E * TPE)                 // 11264
#define TS_GU ((H / 64) * (FS / 64))   // 2048
#define TS_D ((FS / 64) * (H / 64))    // 2048
#define PREP_TR (3 * NT_E + 2 * TS_GU + TS_D)  // 39936
#define PREP_GRID (PREP_TR + T / 8)            // 40192

typedef __bf16 bf16;
typedef bf16 bf16x4 __attribute__((ext_vector_type(4)));
typedef bf16 bf16x8 __attribute__((ext_vector_type(8)));
typedef float floatx4 __attribute__((ext_vector_type(4)));

static __device__ __forceinline__ floatx4 mfma16(bf16x8 a, bf16x8 b, floatx4 c) {
    return __builtin_amdgcn_mfma_f32_16x16x32_bf16(a, b, c, 0, 0, 0);
}

// async global->LDS, 16B per lane; LDS dest must be wave-uniform (HW adds lane*16)
static __device__ __forceinline__ void gload16(const bf16* g, bf16* l) {
    __builtin_amdgcn_global_load_lds(
        (const __attribute__((address_space(1))) void*)g,
        (__attribute__((address_space(3))) void*)l, 16, 0, 0);
}

// ---------------- router ----------------
__global__ __launch_bounds__(256) void router_kernel(
    const float* __restrict__ x, const float* __restrict__ wr,
    int* __restrict__ cnt, int* __restrict__ tokid, float* __restrict__ tokw,
    int* __restrict__ tokslot) {
    const int wave = threadIdx.x >> 6;
    const int lane = threadIdx.x & 63;
    const int t = blockIdx.x * 4 + wave;
    if (t >= T) return;
    const float* xrow = x + (size_t)t * H;
    float xr[H / 64];
#pragma unroll
    for (int i = 0; i < H / 64; i++) xr[i] = xrow[lane + i * 64];
    float logits[E];
    for (int e = 0; e < E; e++) {
        const float* wrow = wr + (size_t)e * H;
        float p = 0.f;
#pragma unroll
        for (int i = 0; i < H / 64; i++) p += xr[i] * wrow[lane + i * 64];
        for (int off = 32; off; off >>= 1) p += __shfl_xor(p, off, 64);
        logits[e] = p;
    }
    float mx = logits[0];
    for (int e = 1; e < E; e++) mx = fmaxf(mx, logits[e]);
    float pr[E];
    float sum = 0.f;
    for (int e = 0; e < E; e++) { pr[e] = __expf(logits[e] - mx); sum += pr[e]; }
    float inv = 1.f / sum;
    for (int e = 0; e < E; e++) pr[e] *= inv;
    int sel[TOPK]; float sw[TOPK]; float wsum = 0.f;
    for (int k = 0; k < TOPK; k++) {
        float best = -1.f; int bi = 0;
        for (int e = 0; e < E; e++) if (pr[e] > best) { best = pr[e]; bi = e; }
        sel[k] = bi; sw[k] = best; wsum += best; pr[bi] = -2.f;
    }
    if (lane == 0) {
        float invw = 1.f / wsum;
        for (int k = 0; k < TOPK; k++) {
            int e = sel[k];
            int pos = atomicAdd(&cnt[e], 1);
            tokid[e * CAP + pos] = t;
            tokw[e * CAP + pos] = sw[k] * invw;
            tokslot[t * TOPK + k] = (e << 16) | pos;
        }
    }
}

// prefix with per-expert padding to 128 rows
__global__ void prefix_kernel(const int* __restrict__ cnt, int* __restrict__ prefix) {
    if (threadIdx.x == 0) {
        int s = 0;
        for (int e = 0; e < E; e++) { prefix[e] = s; s += (cnt[e] + 127) & ~127; }
        prefix[E] = s;
    }
}

// ---------------- prep: all weight transposes + x convert, one dispatch ----------------
// transpose fp32 [z][R][C] -> bf16 [z][C][R] with (row&7)<<3 k-group XOR swizzle;
// x: fp32 [T][H] -> bf16 swizzled (no transpose).
__global__ __launch_bounds__(256) void prep_kernel(
    const float* __restrict__ Wg, const float* __restrict__ Wu,
    const float* __restrict__ Wd, const float* __restrict__ Wgs,
    const float* __restrict__ Wus, const float* __restrict__ Wds,
    const float* __restrict__ x,
    bf16* __restrict__ WgT, bf16* __restrict__ WuT, bf16* __restrict__ WdT,
    bf16* __restrict__ WgsT, bf16* __restrict__ WusT, bf16* __restrict__ WdsT,
    bf16* __restrict__ Xb) {
    __shared__ float tile[64][65];
    const int id = blockIdx.x;
    const int t = threadIdx.x;
    if (id >= PREP_TR) {
        // convert x rows (8 rows per block)
        const int row = (id - PREP_TR) * 8 + (t >> 5);
        const int l32 = t & 31;
        const float* src = x + (size_t)row * H;
        bf16* dst = Xb + (size_t)row * H;
        const int xk = (row & 7) << 3;
#pragma unroll
        for (int i = 0; i < 8; i++) {
            int kb = l32 * 8 + i * 256;
            float4 a = *(const float4*)(src + kb);
            float4 b = *(const float4*)(src + kb + 4);
            bf16x8 v;
            v[0] = (bf16)a.x; v[1] = (bf16)a.y; v[2] = (bf16)a.z; v[3] = (bf16)a.w;
            v[4] = (bf16)b.x; v[5] = (bf16)b.y; v[6] = (bf16)b.z; v[7] = (bf16)b.w;
            *(bf16x8*)(dst + (kb ^ xk)) = v;
        }
        return;
    }
    const float* src; bf16* dst; int R, C, r0, c0;
    size_t zoff = 0;
    if (id < 2 * NT_E) {
        const int which = id / NT_E;
        const int rem = id % NT_E;
        const int e = rem / TPE, tl = rem % TPE;
        R = H; C = F;
        r0 = (tl / (F / 64)) * 64; c0 = (tl % (F / 64)) * 64;
        src = which ? Wu : Wg; dst = which ? WuT : WgT;
        zoff = (size_t)e * H * F;
    } else if (id < 3 * NT_E) {
        const int rem = id - 2 * NT_E;
        const int e = rem / TPE, tl = rem % TPE;
        R = F; C = H;
        r0 = (tl / (H / 64)) * 64; c0 = (tl % (H / 64)) * 64;
        src = Wd; dst = WdT;
        zoff = (size_t)e * F * H;
    } else if (id < 3 * NT_E + 2 * TS_GU) {
        const int rem = id - 3 * NT_E;
        const int which = rem / TS_GU, tl = rem % TS_GU;
        R = H; C = FS;
        r0 = (tl / (FS / 64)) * 64; c0 = (tl % (FS / 64)) * 64;
        src = which ? Wus : Wgs; dst = which ? WusT : WgsT;
    } else {
        const int tl = id - 3 * NT_E - 2 * TS_GU;
        R = FS; C = H;
        r0 = (tl / (H / 64)) * 64; c0 = (tl % (H / 64)) * 64;
        src = Wds; dst = WdsT;
    }
    {   // read 64x64 fp32 tile (coalesced 256B/row)
        const int rl = t >> 2, cq = (t & 3) * 16;
        const float* s = src + zoff + (size_t)(r0 + rl) * C + c0 + cq;
        float4 v0 = ((const float4*)s)[0];
        float4 v1 = ((const float4*)s)[1];
        float4 v2 = ((const float4*)s)[2];
        float4 v3 = ((const float4*)s)[3];
        float* tr = &tile[rl][cq];
        tr[0] = v0.x; tr[1] = v0.y; tr[2] = v0.z; tr[3] = v0.w;
        tr[4] = v1.x; tr[5] = v1.y; tr[6] = v1.z; tr[7] = v1.w;
        tr[8] = v2.x; tr[9] = v2.y; tr[10] = v2.z; tr[11] = v2.w;
        tr[12] = v3.x; tr[13] = v3.y; tr[14] = v3.z; tr[15] = v3.w;
    }
    __syncthreads();
#pragma unroll
    for (int p = 0; p < 2; p++) {  // write transposed: 8 lanes cover 64 rows of one col
        const int cl = p * 32 + (t >> 3);
        const int r8 = (t & 7) * 8;
        bf16x8 o;
#pragma unroll
        for (int i = 0; i < 8; i++) o[i] = (bf16)tile[r8 + i][cl];
        const int cg = c0 + cl;
        *(bf16x8*)(dst + zoff + (size_t)cg * R + ((r0 + r8) ^ ((cg & 7) << 3))) = o;
    }
}

// ---------------- pre-pass: gathered+scaled expert tokens ----------------
__global__ __launch_bounds__(256) void gather_x(
    const float* __restrict__ x, const int* __restrict__ cnt,
    const int* __restrict__ prefixPad, const int* __restrict__ tokid,
    const float* __restrict__ tokw, bf16* __restrict__ Xg) {
    const int e = blockIdx.y;
    const int s0 = blockIdx.x * 8;
    const int n = cnt[e];
    if (s0 >= n) return;
    const int t = threadIdx.x;
    const int sl = s0 + (t >> 5);
    const int l32 = t & 31;
    if (sl >= n) return;
    const int tok = tokid[e * CAP + sl];
    const float w = tokw[e * CAP + sl];
    const int row = prefixPad[e] + sl;
    const float* src = x + (size_t)tok * H;
    bf16* dst = Xg + (size_t)row * H;
    const int xk = (row & 7) << 3;
#pragma unroll
    for (int i = 0; i < 8; i++) {
        int kb = l32 * 8 + i * 256;
        float4 a = *(const float4*)(src + kb);
        float4 b = *(const float4*)(src + kb + 4);
        bf16x8 v;
        v[0] = (bf16)(a.x * w); v[1] = (bf16)(a.y * w);
        v[2] = (bf16)(a.z * w); v[3] = (bf16)(a.w * w);
        v[4] = (bf16)(b.x * w); v[5] = (bf16)(b.y * w);
        v[6] = (bf16)(b.z * w); v[7] = (bf16)(b.w * w);
        *(bf16x8*)(dst + (kb ^ xk)) = v;
    }
}

// ---------------- merged stage 1: shared + expert FFN1 ----------------
__global__ __launch_bounds__(256, 3) void s1_all(
    const bf16* __restrict__ Xb, const bf16* __restrict__ Xg,
    const bf16* __restrict__ WgsT, const bf16* __restrict__ WusT,
    const bf16* __restrict__ WgT, const bf16* __restrict__ WuT,
    bf16* __restrict__ Hs, bf16* __restrict__ Hb,
    const int* __restrict__ cnt, const int* __restrict__ prefixPad) {
    __shared__ __align__(16) bf16 As[128 * 64];
    __shared__ __align__(16) bf16 Bgs[128 * 64];
    __shared__ __align__(16) bf16 Bus[128 * 64];

    const int raw = blockIdx.x;
    const int id = (raw & 7) * (GS1 / 8) + (raw >> 3);  // XCD-chunked

    int n0, m0, ne, nF;
    const bf16 *A, *bg, *bu;
    bf16* hb;
    if (id < NS) {
        m0 = (id & 15) * 128;
        n0 = (id >> 4) * 128;
        ne = 1 << 30;
        nF = FS;
        A = Xb; bg = WgsT; bu = WusT; hb = Hs;
    } else {
        const int id2 = id - NS;
        const int mb = id2 % NMB;   // m fast -> B panel L2-hot
        const int xx = id2 / NMB;
        const int rowbase = mb * 128;
        if (rowbase >= prefixPad[E]) return;
        int e = 0;
        while (prefixPad[e + 1] <= rowbase) e++;
        const int pp = prefixPad[e];
        m0 = rowbase - pp;
        ne = cnt[e];
        n0 = xx * 128;
        nF = F;
        A = Xg + (size_t)pp * H;
        bg = WgT + (size_t)e * F * H;
        bu = WuT + (size_t)e * F * H;
        hb = Hb + (size_t)pp * F;
    }

    const int tid = threadIdx.x;
    const int lane = tid & 63;
    const int wave = tid >> 6;
    const bf16* aP = A + (size_t)(m0 + wave * 32 + (lane >> 3)) * H + (lane & 7) * 8;
    const bf16* gP = bg + (size_t)(n0 + wave * 32 + (lane >> 3)) * H + (lane & 7) * 8;
    const bf16* uP = bu + (size_t)(n0 + wave * 32 + (lane >> 3)) * H + (lane & 7) * 8;

    const int m_ = lane & 15;
    const int quad = lane >> 4;
    const int wm = (wave & 1) * 64;
    const int wn = (wave >> 1) * 64;

    floatx4 accg[4][4], accu[4][4];
#pragma unroll
    for (int i = 0; i < 4; i++)
#pragma unroll
        for (int j = 0; j < 4; j++) {
            accg[i][j] = (floatx4){0.f, 0.f, 0.f, 0.f};
            accu[i][j] = (floatx4){0.f, 0.f, 0.f, 0.f};
        }

    for (int k0 = 0; k0 < H; k0 += 64) {
#pragma unroll
        for (int j = 0; j < 4; j++) {
            gload16(aP + k0 + (size_t)j * 8 * H, &As[wave * 2048 + j * 512]);
            gload16(gP + k0 + (size_t)j * 8 * H, &Bgs[wave * 2048 + j * 512]);
            gload16(uP + k0 + (size_t)j * 8 * H, &Bus[wave * 2048 + j * 512]);
        }
        __syncthreads();
#pragma unroll
        for (int kk = 0; kk < 2; kk++) {
            const int ko = (((kk << 2) | quad) ^ (m_ & 7)) << 3;
            bf16x8 af[4], bgf[4], buf_[4];
#pragma unroll
            for (int mi = 0; mi < 4; mi++)
                af[mi] = *(const bf16x8*)&As[(wm + mi * 16 + m_) * 64 + ko];
#pragma unroll
            for (int ni = 0; ni < 4; ni++) {
                bgf[ni] = *(const bf16x8*)&Bgs[(wn + ni * 16 + m_) * 64 + ko];
                buf_[ni] = *(const bf16x8*)&Bus[(wn + ni * 16 + m_) * 64 + ko];
            }
#pragma unroll
            for (int mi = 0; mi < 4; mi++)
#pragma unroll
                for (int ni = 0; ni < 4; ni++) {
                    accg[mi][ni] = mfma16(af[mi], bgf[ni], accg[mi][ni]);
                    accu[mi][ni] = mfma16(af[mi], buf_[ni], accu[mi][ni]);
                }
        }
        __syncthreads();
    }

#pragma unroll
    for (int mi = 0; mi < 4; mi++)
#pragma unroll
        for (int ni = 0; ni < 4; ni++)
#pragma unroll
            for (int r = 0; r < 4; r++) {
                int row = m0 + wm + mi * 16 + quad * 4 + r;
                int col = n0 + wn + ni * 16 + m_;
                if (row < ne) {
                    float g = accg[mi][ni][r];
                    float u = accu[mi][ni][r];
                    float hv = g / (1.f + __expf(-g)) * u;
                    hb[(size_t)row * nF + (col ^ ((row & 7) << 3))] = (bf16)hv;
                }
            }
}

// ---------------- merged stage 2: shared -> out (exact), expert -> partial (no atomics) ----------------
__global__ __launch_bounds__(256, 4) void s2_all(
    const bf16* __restrict__ Hs, const bf16* __restrict__ Hb,
    const bf16* __restrict__ WdsT, const bf16* __restrict__ WdT,
    float* __restrict__ out, float* __restrict__ partial,
    const int* __restrict__ cnt, const int* __restrict__ prefixPad,
    const float* __restrict__ tokw) {
    __shared__ __align__(16) bf16 As[128 * 64];
    __shared__ __align__(16) bf16 Bs[128 * 64];
    const int raw = blockIdx.x;
    const int id = (raw & 7) * (GS2 / 8) + (raw >> 3);  // 1536 divisible by 8
    int n0, m0, ne, nK, e = 0, pp = 0;
    const bf16 *A, *B;
    bool expert;
    if (id < (H / 128) * (T / 128)) {
        m0 = (id & 15) * 128;
        n0 = (id >> 4) * 128;
        ne = 1 << 30;
        A = Hs; B = WdsT; nK = FS; expert = false;
    } else {
        const int id2 = id - (H / 128) * (T / 128);
        const int mb = id2 % NMB;
        const int xx = id2 / NMB;
        const int rowbase = mb * 128;
        if (rowbase >= prefixPad[E]) return;
        while (prefixPad[e + 1] <= rowbase) e++;
        pp = prefixPad[e];
        m0 = rowbase - pp;
        ne = cnt[e];
        n0 = xx * 128;
        A = Hb + (size_t)pp * F;
        B = WdT + (size_t)e * F * H;
        nK = F; expert = true;
    }
    const int tid = threadIdx.x;
    const int lane = tid & 63;
    const int wave = tid >> 6;
    const bf16* aP = A + (size_t)(m0 + wave * 32 + (lane >> 3)) * nK + (lane & 7) * 8;
    const bf16* bP = B + (size_t)(n0 + wave * 32 + (lane >> 3)) * nK + (lane & 7) * 8;

    const int m_ = lane & 15;
    const int quad = lane >> 4;
    const int wm = (wave & 1) * 64;
    const int wn = (wave >> 1) * 64;

    floatx4 acc[4][4];
#pragma unroll
    for (int i = 0; i < 4; i++)
#pragma unroll
        for (int j = 0; j < 4; j++) acc[i][j] = (floatx4){0.f, 0.f, 0.f, 0.f};

    for (int k0 = 0; k0 < nK; k0 += 64) {
#pragma unroll
        for (int j = 0; j < 4; j++) {
            gload16(aP + k0 + (size_t)j * 8 * nK, &As[wave * 2048 + j * 512]);
            gload16(bP + k0 + (size_t)j * 8 * nK, &Bs[wave * 2048 + j * 512]);
        }
        __syncthreads();
#pragma unroll
        for (int kk = 0; kk < 2; kk++) {
            const int ko = (((kk << 2) | quad) ^ (m_ & 7)) << 3;
            bf16x8 af[4], bf_[4];
#pragma unroll
            for (int mi = 0; mi < 4; mi++)
                af[mi] = *(const bf16x8*)&As[(wm + mi * 16 + m_) * 64 + ko];
#pragma unroll
            for (int ni = 0; ni < 4; ni++)
                bf_[ni] = *(const bf16x8*)&Bs[(wn + ni * 16 + m_) * 64 + ko];
#pragma unroll
            for (int mi = 0; mi < 4; mi++)
#pragma unroll
                for (int ni = 0; ni < 4; ni++)
                    acc[mi][ni] = mfma16(af[mi], bf_[ni], acc[mi][ni]);
        }
        __syncthreads();
    }

#pragma unroll
    for (int mi = 0; mi < 4; mi++)
#pragma unroll
        for (int ni = 0; ni < 4; ni++)
#pragma unroll
            for (int r = 0; r < 4; r++) {
                int row = m0 + wm + mi * 16 + quad * 4 + r;
                int col = n0 + wn + ni * 16 + m_;
                if (expert) {
                    if (row < ne) {
                        float wgt = tokw[e * CAP + row];
                        partial[(size_t)(pp + row) * H + col] = acc[mi][ni][r] * wgt;
                    }
                } else {
                    out[(size_t)row * H + col] = acc[mi][ni][r];
                }
            }
}

// ---------------- final: out[t] += sum of the token's 4 expert partial rows ----------------
__global__ __launch_bounds__(256) void final_add(
    float* __restrict__ out, const float* __restrict__ partial,
    const int* __restrict__ tokslot, const int* __restrict__ prefixPad) {
    const int t = blockIdx.x;
    const int tid = threadIdx.x;
    int prow[TOPK];
#pragma unroll
    for (int k = 0; k < TOPK; k++) {
        int s = tokslot[t * TOPK + k];
        prow[k] = prefixPad[s >> 16] + (s & 0xffff);
    }
    float4* o = (float4*)(out + (size_t)t * H);
#pragma unroll
    for (int i = 0; i < H / 4 / 256; i++) {
        int idx = tid + i * 256;
        float4 v = o[idx];
#pragma unroll
        for (int k = 0; k < TOPK; k++) {
            float4 p = ((const float4*)(partial + (size_t)prow[k] * H))[idx];
            v.x += p.x; v.y += p.y; v.z += p.z; v.w += p.w;
        }
        o[idx] = v;
    }
}

extern "C" void kernel_launch(void* const* d_in, const int* in_sizes, int n_in,
                              void* d_out, int out_size, void* d_ws, size_t ws_size,
                              hipStream_t stream) {
    const float* x = (const float*)d_in[0];
    const float* w_router = (const float*)d_in[1];
    const float* Wg = (const float*)d_in[2];
    const float* Wu = (const float*)d_in[3];
    const float* Wd = (const float*)d_in[4];
    const float* Wg_s = (const float*)d_in[5];
    const float* Wu_s = (const float*)d_in[6];
    const float* Wd_s = (const float*)d_in[7];
    float* out = (float*)d_out;

    char* w = (char*)d_ws;
    int* cnt = (int*)(w + 0);
    int* prefix = (int*)(w + 64);
    int* tokid = (int*)(w + 256);
    float* tokw = (float*)(w + 256 + (size_t)E * CAP * 4);

    constexpr size_t OFF_TOKSLOT = 262400;                      // T*TOPK*4 = 32 KB
    constexpr size_t OFF_XB = OFF_TOKSLOT + (size_t)T * TOPK * 4;
    constexpr size_t OFF_XG = OFF_XB + (size_t)T * H * 2;
    constexpr size_t OFF_HS = OFF_XG + (size_t)NPADROWS * H * 2;
    constexpr size_t OFF_HB = OFF_HS + (size_t)T * FS * 2;
    constexpr size_t OFF_WGT = OFF_HB + (size_t)NPADROWS * F * 2;
    constexpr size_t OFF_WUT = OFF_WGT + (size_t)E * F * H * 2;
    constexpr size_t OFF_WDT = OFF_WUT + (size_t)E * F * H * 2;
    constexpr size_t OFF_WGS = OFF_WDT + (size_t)E * F * H * 2;
    constexpr size_t OFF_WUS = OFF_WGS + (size_t)H * FS * 2;
    constexpr size_t OFF_WDS = OFF_WUS + (size_t)H * FS * 2;

    int* tokslot = (int*)(w + OFF_TOKSLOT);
    bf16* Xb = (bf16*)(w + OFF_XB);
    bf16* Xg = (bf16*)(w + OFF_XG);
    bf16* Hs = (bf16*)(w + OFF_HS);
    bf16* Hb = (bf16*)(w + OFF_HB);
    bf16* WgT = (bf16*)(w + OFF_WGT);
    bf16* WuT = (bf16*)(w + OFF_WUT);
    bf16* WdT = (bf16*)(w + OFF_WDT);
    bf16* WgsT = (bf16*)(w + OFF_WGS);
    bf16* WusT = (bf16*)(w + OFF_WUS);
    bf16* WdsT = (bf16*)(w + OFF_WDS);
    // partial (NPADROWS*H*4 = 83.9 MB) aliases WgT (92.3 MB): WgT is dead after
    // s1_all completes, and s2_all (which writes partial) is stream-ordered after it.
    float* partial = (float*)(w + OFF_WGT);

    hipMemsetAsync(cnt, 0, 64, stream);
    router_kernel<<<T / 4, 256, 0, stream>>>(x, w_router, cnt, tokid, tokw, tokslot);
    prefix_kernel<<<1, 64, 0, stream>>>(cnt, prefix);
    gather_x<<<dim3(CAP / 8, E), 256, 0, stream>>>(x, cnt, prefix, tokid, tokw, Xg);
    prep_kernel<<<PREP_GRID, 256, 0, stream>>>(Wg, Wu, Wd, Wg_s, Wu_s, Wd_s, x,
                                               WgT, WuT, WdT, WgsT, WusT, WdsT, Xb);

    s1_all<<<GS1, 256, 0, stream>>>(Xb, Xg, WgsT, WusT, WgT, WuT, Hs, Hb, cnt, prefix);
    s2_all<<<GS2, 256, 0, stream>>>(Hs, Hb, WdsT, WdT, out, partial, cnt, prefix, tokw);
    final_add<<<T, 256, 0, stream>>>(out, partial, tokslot, prefix);
}